// Round 8
// baseline (4521.865 us; speedup 1.0000x reference)
//
#include <hip/hip_runtime.h>
#include <hip/hip_bf16.h>

// ---------------- problem constants ----------------
#define TSEQ 512
#define NB   64
#define NE   256
#define NH   512
#define NG   2048   // 4*NH

// ---------------- workspace layout (bytes) ----------------
static const size_t OFF_W1  = 0;          // 6,291,456
static const size_t OFF_W2  = 6291456;    // 8,388,608
static const size_t OFF_X   = 14680064;   // 16,777,216  (fragment-linear per t)
static const size_t OFF_H1  = 31457280;   // 2 dir * 4 slot * 64KB = 524,288
static const size_t OFF_H2  = 31981568;   // 524,288
static const size_t OFF_HF  = 32505856;   // 131,072
static const size_t OFF_CNT = 32636928;   // tags: 4 sets * 4096-int stride (single replica per (wv,slice))

typedef __bf16 v8bf __attribute__((ext_vector_type(8)));
typedef float  v4f  __attribute__((ext_vector_type(4)));

#define MFMA16(a_, b_, c_) __builtin_amdgcn_mfma_f32_16x16x32_bf16((a_), (b_), (c_), 0, 0, 0)

// Coherent 16B h-fragment load: two 8B relaxed agent-scope atomic loads.
// Compiler-managed waitcnt (robust under spills). Fragment-linear layout makes
// the 64 lanes' addresses contiguous -> coalesced.
static __device__ __forceinline__ v8bf load_h8(const __bf16* p) {
    unsigned long long lo = __hip_atomic_load((unsigned long long*)p,     __ATOMIC_RELAXED, __HIP_MEMORY_SCOPE_AGENT);
    unsigned long long hi = __hip_atomic_load((unsigned long long*)p + 1, __ATOMIC_RELAXED, __HIP_MEMORY_SCOPE_AGENT);
    union { unsigned long long q[2]; v8bf v; } u;
    u.q[0] = lo; u.q[1] = hi;
    return u.v;
}

static __device__ __forceinline__ unsigned short bf16_bits(float f) {
    __bf16 b = (__bf16)f;
    return __builtin_bit_cast(unsigned short, b);
}

// ---------------- phase A: weight convert to fragment-linear bf16 ----------------
__global__ void wconv_kernel(const float* __restrict__ Wf, const float* __restrict__ Uf,
                             const float* __restrict__ Wb, const float* __restrict__ Ub,
                             char* __restrict__ dst, int NC, int KX)
{
    int id = blockIdx.x * 256 + threadIdx.x;
    int j    = id & 7;
    int lane = (id >> 3) & 63;
    int t    = (id >> 9) & 1;
    int rest = id >> 10;            // (dir*64+slice)*NC + c
    int c    = rest % NC;
    int ds   = rest / NC;
    int slice = ds & 63;
    int dirr  = ds >> 6;
    int coll = t * 16 + (lane & 15);
    int k    = c * 32 + (lane >> 4) * 8 + j;
    int gate = coll >> 3, jjj = coll & 7;
    int zcol = gate * 512 + slice * 8 + jjj;
    const float* W = dirr ? Wb : Wf;
    const float* U = dirr ? Ub : Uf;
    float v = (k < KX) ? W[(size_t)k * NG + zcol] : U[(size_t)(k - KX) * NG + zcol];
    ((__bf16*)dst)[id] = (__bf16)v;
}

// ---------------- phase A: embedding gather into fragment-linear X + tag zero ----------------
// X element (t, b=m, e) stored at byte: t*32768 + ((e>>3)*64 + m)*16 + (e&7)*2
__global__ void gather_x_kernel(const int* __restrict__ tokens, const float* __restrict__ emb,
                                char* __restrict__ ws)
{
    size_t id = (size_t)blockIdx.x * 256 + threadIdx.x;
    int j  = (int)(id & 7);
    int m  = (int)((id >> 3) & 63);
    int kb = (int)((id >> 9) & 31);
    int t  = (int)(id >> 14);
    int tok = tokens[m * TSEQ + t];
    float v = emb[(size_t)tok * NE + kb * 8 + j];
    ((__bf16*)(ws + OFF_X))[(size_t)t * 16384 + (kb * 64 + m) * 8 + j] = (__bf16)v;
    if (id < 16384) ((int*)(ws + OFF_CNT))[id] = 0;    // whole tag region
}

// ---------------- phase B: persistent pipelined recurrence ----------------
// Byte-identical protocol to R4 (ring depth 4, slot stride 32768 bf16, drained
// tag publish, coalesced full-line h stores) with ONE change: tags are a SINGLE
// line-set instead of x16 replicas. Counter accounting showed the 16-replica
// publish was ~100% of the dispatch's HBM WRITE_SIZE (contended-line 64B
// write-through per 4B store); collapsing to one store per wave per step cuts
// that churn 16x. Tag address: T[set*4096 + wv*64 + slice].
template<int LAYER>
__device__ void run_layer(char* __restrict__ ws, const char* __restrict__ smem,
                          int dir, int slice, int tid,
                          const float* __restrict__ bb)
{
    const int lane = tid & 63;
    const int wv   = tid >> 6;
    const int colc = lane & 15;
    const int q    = lane >> 4;
    const int m0   = wv * 16;
    const int jj   = colc & 7;
    const int hcol = slice * 8 + jj;

    __bf16* h1ring = (__bf16*)(ws + OFF_H1 + (size_t)dir * (4 * 65536));
    __bf16* h2ring = (__bf16*)(ws + OFF_H2 + (size_t)dir * (4 * 65536));
    const char* Xfrag = ws + OFF_X;
    __bf16* hfin = (__bf16*)(ws + OFF_HF) + (size_t)dir * (NB * NH);

    // tags (single replica): T[(dir*2+layer)*4096 + wv*64 + slice]
    int* T = (int*)(ws + OFF_CNT);
    int* p1   = T + (dir * 2 + 0) * 4096 + wv * 64 + lane;   // poll L1 producers (lane = slice)
    int* p2   = T + (dir * 2 + 1) * 4096 + wv * 64 + lane;   // poll L2 producers
    int* ownp = T + (dir * 2 + LAYER) * 4096 + wv * 64 + slice;   // own publish element

    const float bi  = bb[hcol];
    const float bf_ = bb[512 + hcol];
    const float bg  = bb[1024 + hcol];
    const float bo  = bb[1536 + hcol];

    float cst[4] = {0.f, 0.f, 0.f, 0.f};

    // h-fragment element offset for consumer loads (in __bf16 units)
    const int aoff = (m0 + colc) * 8;

    #pragma unroll 1
    for (int s = 0; s < TSEQ; ++s) {
        v4f acc0a = {0,0,0,0}, acc1a = {0,0,0,0};
        v4f acc0b = {0,0,0,0}, acc1b = {0,0,0,0};

        // ---- L1: x-part (no step dependency) computed BEFORE the poll ----
        if (LAYER == 0) {
            const int xs = dir ? (TSEQ - 1 - s) : s;
            const char* xb = Xfrag + (size_t)xs * 32768;
            #pragma unroll
            for (int c = 0; c < 8; ++c) {
                v8bf a  = *(const v8bf*)(xb + (((4 * c + q) * 64 + m0 + colc) * 16));
                v8bf w0 = *(const v8bf*)(smem + (c * 2 + 0) * 1024 + lane * 16);
                v8bf w1 = *(const v8bf*)(smem + (c * 2 + 1) * 1024 + lane * 16);
                if (c & 1) { acc0b = MFMA16(a, w0, acc0b); acc1b = MFMA16(a, w1, acc1b); }
                else       { acc0a = MFMA16(a, w0, acc0a); acc1a = MFMA16(a, w1, acc1a); }
            }
        }

        // ---- lane-parallel poll on single-replica per-wave tags ----
        // L1 step s: p1 >= s (h1[s-1] ready), p2 >= s-3 (ring guard)
        // L2 step s: p1 >= s+1 (h1[s] ready), p2 >= s (h2[s-1] ready)
        {
            const int t1 = LAYER ? s + 1 : s;
            const int t2 = LAYER ? s : s - 3;
            if (t1 > 0) {
                while (true) {
                    int v1 = __hip_atomic_load(p1, __ATOMIC_RELAXED, __HIP_MEMORY_SCOPE_AGENT);
                    bool ok = (v1 >= t1);
                    if (t2 > 0) {
                        int v2 = __hip_atomic_load(p2, __ATOMIC_RELAXED, __HIP_MEMORY_SCOPE_AGENT);
                        ok = ok && (v2 >= t2);
                    }
                    if (__all(ok)) break;
                }
            }
        }

        // ---- h-dependent MFMA work (coalesced coherent loads, LDS weights) ----
        if (LAYER == 0) {
            if (s > 0) {
                const __bf16* hb = h1ring + (size_t)((s - 1) & 3) * 32768;
                v8bf ah[16];
                #pragma unroll
                for (int c = 0; c < 16; ++c)
                    ah[c] = load_h8(hb + (4 * c + q) * 512 + aoff);
                __builtin_amdgcn_sched_barrier(0);   // keep the load batch together
                #pragma unroll
                for (int c = 0; c < 16; ++c) {
                    v8bf w0 = *(const v8bf*)(smem + ((8 + c) * 2 + 0) * 1024 + lane * 16);
                    v8bf w1 = *(const v8bf*)(smem + ((8 + c) * 2 + 1) * 1024 + lane * 16);
                    if (c & 1) { acc0b = MFMA16(ah[c], w0, acc0b); acc1b = MFMA16(ah[c], w1, acc1b); }
                    else       { acc0a = MFMA16(ah[c], w0, acc0a); acc1a = MFMA16(ah[c], w1, acc1a); }
                }
            }
        } else {
            const __bf16* hb1 = h1ring + (size_t)(s & 3) * 32768;
            v8bf a0[16], a1[16];
            #pragma unroll
            for (int c = 0; c < 16; ++c)
                a0[c] = load_h8(hb1 + (4 * c + q) * 512 + aoff);
            if (s > 0) {
                const __bf16* hb2 = h2ring + (size_t)((s - 1) & 3) * 32768;
                #pragma unroll
                for (int c = 0; c < 16; ++c)
                    a1[c] = load_h8(hb2 + (4 * c + q) * 512 + aoff);
            }
            __builtin_amdgcn_sched_barrier(0);
            #pragma unroll
            for (int c = 0; c < 16; ++c) {
                v8bf w0 = *(const v8bf*)(smem + (c * 2 + 0) * 1024 + lane * 16);
                v8bf w1 = *(const v8bf*)(smem + (c * 2 + 1) * 1024 + lane * 16);
                if (c & 1) { acc0b = MFMA16(a0[c], w0, acc0b); acc1b = MFMA16(a0[c], w1, acc1b); }
                else       { acc0a = MFMA16(a0[c], w0, acc0a); acc1a = MFMA16(a0[c], w1, acc1a); }
            }
            if (s > 0) {
                #pragma unroll
                for (int c = 0; c < 16; ++c) {
                    v8bf w0 = *(const v8bf*)(smem + ((16 + c) * 2 + 0) * 1024 + lane * 16);
                    v8bf w1 = *(const v8bf*)(smem + ((16 + c) * 2 + 1) * 1024 + lane * 16);
                    if (c & 1) { acc0b = MFMA16(a1[c], w0, acc0b); acc1b = MFMA16(a1[c], w1, acc1b); }
                    else       { acc0a = MFMA16(a1[c], w0, acc0a); acc1a = MFMA16(a1[c], w1, acc1a); }
                }
            }
        }

        v4f z0 = acc0a + acc0b;   // gates i (cols 0-7) / f (cols 8-15)
        v4f z1 = acc1a + acc1b;   // gates g / o

        // ---- gate nonlinearity; lanes col and col^8 exchange ----
        float hv[4];
        #pragma unroll
        for (int r = 0; r < 4; ++r) {
            float p0 = __shfl_xor(z0[r], 8, 64);
            float p1 = __shfl_xor(z1[r], 8, 64);
            float zi, zf, zg, zo;
            if (colc < 8) { zi = z0[r]; zf = p0;    zg = z1[r]; zo = p1;    }
            else          { zi = p0;    zf = z0[r]; zg = p1;    zo = z1[r]; }
            zi += bi; zf += bf_; zg += bg; zo += bo;
            float gi = 1.f / (1.f + __expf(-zi));
            float gf = 1.f / (1.f + __expf(-zf));
            float gg = 1.f - 2.f / (1.f + __expf(2.f * zg));   // tanh
            float go = 1.f / (1.f + __expf(-zo));
            float cn = gf * cst[r] + gi * gg;
            cst[r] = cn;
            float th = 1.f - 2.f / (1.f + __expf(2.f * cn));   // tanh
            hv[r] = go * th;
        }

        // ---- coalesced h store: 4x4 lane transpose -> one 16B row per lane (R4) ----
        __bf16* hd = (LAYER ? h2ring : h1ring) + (size_t)(s & 3) * 32768;
        {
            unsigned u0, u1, u2, u3;
            {
                float pv0 = __shfl_xor(hv[0], 1, 64);
                float pv1 = __shfl_xor(hv[1], 1, 64);
                float pv2 = __shfl_xor(hv[2], 1, 64);
                float pv3 = __shfl_xor(hv[3], 1, 64);
                u0 = (unsigned)bf16_bits(hv[0]) | ((unsigned)bf16_bits(pv0) << 16);
                u1 = (unsigned)bf16_bits(hv[1]) | ((unsigned)bf16_bits(pv1) << 16);
                u2 = (unsigned)bf16_bits(hv[2]) | ((unsigned)bf16_bits(pv2) << 16);
                u3 = (unsigned)bf16_bits(hv[3]) | ((unsigned)bf16_bits(pv3) << 16);
            }
            const bool sel1 = (colc & 2) != 0;
            const bool sel2 = (colc & 4) != 0;
            unsigned t;
            t = __shfl_xor(sel1 ? u0 : u1, 2, 64); if (sel1) u0 = t; else u1 = t;
            t = __shfl_xor(sel1 ? u2 : u3, 2, 64); if (sel1) u2 = t; else u3 = t;
            t = __shfl_xor(sel2 ? u0 : u2, 4, 64); if (sel2) u0 = t; else u2 = t;
            t = __shfl_xor(sel2 ? u1 : u3, 4, 64); if (sel2) u1 = t; else u3 = t;
            if (((colc & 1) == 0) && (colc < 8)) {
                const int m = m0 + q * 4 + (colc >> 1);
                unsigned long long lo = (unsigned long long)u0 | ((unsigned long long)u1 << 32);
                unsigned long long hi = (unsigned long long)u2 | ((unsigned long long)u3 << 32);
                unsigned long long* dp = (unsigned long long*)(hd + (slice * 64 + m) * 8);
                __hip_atomic_store(dp,     lo, __ATOMIC_RELAXED, __HIP_MEMORY_SCOPE_AGENT);
                __hip_atomic_store(dp + 1, hi, __ATOMIC_RELAXED, __HIP_MEMORY_SCOPE_AGENT);
            }
        }
        if (LAYER == 1 && s == TSEQ - 1 && colc < 8) {
            #pragma unroll
            for (int r = 0; r < 4; ++r)
                hfin[(size_t)(m0 + q * 4 + r) * NH + hcol] = (__bf16)hv[r];   // kernel boundary
        }

        // drain this wave's stores (count-independent), then publish ONE tag
        asm volatile("s_waitcnt vmcnt(0)" ::: "memory");
        if (lane == 0)
            __hip_atomic_store(ownp, s + 1, __ATOMIC_RELAXED, __HIP_MEMORY_SCOPE_AGENT);
    }
}

__global__ __launch_bounds__(256, 1) void lstm_persist(
    char* __restrict__ ws,
    const float* __restrict__ b1f, const float* __restrict__ b2f,
    const float* __restrict__ b1b, const float* __restrict__ b2b)
{
    const int tid   = threadIdx.x;
    const int bid   = blockIdx.x;       // 256 wgs
    const int dir   = bid >> 7;
    const int layer = (bid >> 6) & 1;
    const int slice = bid & 63;

    const int NC = layer ? 32 : 24;
    const int wbytes = NC * 2048;       // 48KB (L1) / 64KB (L2)

    __shared__ char smem[65536];
    {
        const char* wsrc = ws + (layer ? OFF_W2 : OFF_W1)
                         + (size_t)(dir * 64 + slice) * (size_t)wbytes;
        for (int i = tid * 16; i < wbytes; i += 256 * 16)
            *(uint4*)(smem + i) = *(const uint4*)(wsrc + i);
    }
    __syncthreads();   // staging is cooperative; only barrier in the kernel

    const float* bb = layer ? (dir ? b2b : b2f) : (dir ? b1b : b1f);
    if (layer == 0) run_layer<0>(ws, smem, dir, slice, tid, bb);
    else            run_layer<1>(ws, smem, dir, slice, tid, bb);
}

// ---------------- phase C: dense head [64,1024]@[1024,5]+bd ----------------
__global__ void head_kernel(const char* __restrict__ ws, const float* __restrict__ Wd,
                            const float* __restrict__ bd, float* __restrict__ out)
{
    int b = blockIdx.x;
    int lane = threadIdx.x;   // 64
    const __bf16* hfF = (const __bf16*)(ws + OFF_HF) + (size_t)b * NH;
    const __bf16* hfB = (const __bf16*)(ws + OFF_HF) + (size_t)(NB * NH) + (size_t)b * NH;
    #pragma unroll
    for (int o = 0; o < 5; ++o) {
        float sum = 0.f;
        for (int k = lane; k < 2 * NH; k += 64) {
            float fv = (k < NH) ? (float)hfF[k] : (float)hfB[k - NH];
            sum += fv * Wd[(size_t)k * 5 + o];
        }
        #pragma unroll
        for (int off = 32; off > 0; off >>= 1) sum += __shfl_down(sum, off, 64);
        if (lane == 0) out[b * 5 + o] = sum + bd[o];
    }
}

// ---------------- launch ----------------
extern "C" void kernel_launch(void* const* d_in, const int* in_sizes, int n_in,
                              void* d_out, int out_size, void* d_ws, size_t ws_size,
                              hipStream_t stream)
{
    const int*   tokens = (const int*)  d_in[0];
    const float* emb    = (const float*)d_in[1];
    const float* W1f    = (const float*)d_in[2];
    const float* U1f    = (const float*)d_in[3];
    const float* b1f    = (const float*)d_in[4];
    const float* W2f    = (const float*)d_in[5];
    const float* U2f    = (const float*)d_in[6];
    const float* b2f    = (const float*)d_in[7];
    const float* W1b    = (const float*)d_in[8];
    const float* U1b    = (const float*)d_in[9];
    const float* b1b    = (const float*)d_in[10];
    const float* W2b    = (const float*)d_in[11];
    const float* U2b    = (const float*)d_in[12];
    const float* b2b    = (const float*)d_in[13];
    const float* Wd     = (const float*)d_in[14];
    const float* bd     = (const float*)d_in[15];
    char* ws = (char*)d_ws;

    wconv_kernel<<<12288, 256, 0, stream>>>(W1f, U1f, W1b, U1b, ws + OFF_W1, 24, 256);
    wconv_kernel<<<16384, 256, 0, stream>>>(W2f, U2f, W2b, U2b, ws + OFF_W2, 32, 512);
    gather_x_kernel<<<32768, 256, 0, stream>>>(tokens, emb, ws);
    lstm_persist<<<256, 256, 0, stream>>>(ws, b1f, b2f, b1b, b2b);
    head_kernel<<<NB, 64, 0, stream>>>(ws, Wd, bd, (float*)d_out);
}

// Round 9
// 3509.421 us; speedup vs baseline: 1.2885x; 1.2885x over previous
//
#include <hip/hip_runtime.h>
#include <hip/hip_bf16.h>

// ============================================================================
// SimpleBiLSTM persistent kernel — FINAL (reverted to the R4 optimum).
//
// Session experiment matrix (512-step MALL-latency-bound recurrence):
//   R4 coalesced-store + drained x16-replica tags ............ 3510 us  <== best
//   R0 scattered 4B stores ................................... 3545 us
//   R2 drain-free + in-band parity validate .................. 3675 us
//   R7 speculative cross-backedge loads + validate ........... 3815 us
//   R3 fused columns (128 wgs, half traffic) ................. 3958 us
//   R8 single tag line (no replication) ...................... 4522 us
//   R1 shadow-plane validation ............................... 4779 us
//   R5 sc0 intra-XCD / R6 atomic-RMW reads ................... broken / 20 ms
// Conclusion: step period ~6.9 us = agent-scope publish->observe->load chain
// + straggler tail; every hop-removal scheme re-pays the same round-trip as a
// retry/poll quantum. x16 tag replication is load-bearing (R8). No HIP-level
// mechanism for faster cross-CU exchange exists on gfx950 (R5/R6).
// ============================================================================

// ---------------- problem constants ----------------
#define TSEQ 512
#define NB   64
#define NE   256
#define NH   512
#define NG   2048   // 4*NH

// ---------------- workspace layout (bytes) ----------------
static const size_t OFF_W1  = 0;          // 6,291,456
static const size_t OFF_W2  = 6291456;    // 8,388,608
static const size_t OFF_X   = 14680064;   // 16,777,216  (fragment-linear per t)
static const size_t OFF_H1  = 31457280;   // 2 dir * 4 slot * 64KB = 524,288
static const size_t OFF_H2  = 31981568;   // 524,288
static const size_t OFF_HF  = 32505856;   // 131,072
static const size_t OFF_CNT = 32636928;   // tags: 4 sets * 16 rep * 256 * 4B = 64 KB

typedef __bf16 v8bf __attribute__((ext_vector_type(8)));
typedef float  v4f  __attribute__((ext_vector_type(4)));

#define MFMA16(a_, b_, c_) __builtin_amdgcn_mfma_f32_16x16x32_bf16((a_), (b_), (c_), 0, 0, 0)

// Coherent 16B h-fragment load: two 8B relaxed agent-scope atomic loads.
// Compiler-managed waitcnt (robust under spills). Fragment-linear layout makes
// the 64 lanes' addresses contiguous -> coalesced.
static __device__ __forceinline__ v8bf load_h8(const __bf16* p) {
    unsigned long long lo = __hip_atomic_load((unsigned long long*)p,     __ATOMIC_RELAXED, __HIP_MEMORY_SCOPE_AGENT);
    unsigned long long hi = __hip_atomic_load((unsigned long long*)p + 1, __ATOMIC_RELAXED, __HIP_MEMORY_SCOPE_AGENT);
    union { unsigned long long q[2]; v8bf v; } u;
    u.q[0] = lo; u.q[1] = hi;
    return u.v;
}

static __device__ __forceinline__ unsigned short bf16_bits(float f) {
    __bf16 b = (__bf16)f;
    return __builtin_bit_cast(unsigned short, b);
}

// ---------------- phase A: weight convert to fragment-linear bf16 ----------------
__global__ void wconv_kernel(const float* __restrict__ Wf, const float* __restrict__ Uf,
                             const float* __restrict__ Wb, const float* __restrict__ Ub,
                             char* __restrict__ dst, int NC, int KX)
{
    int id = blockIdx.x * 256 + threadIdx.x;
    int j    = id & 7;
    int lane = (id >> 3) & 63;
    int t    = (id >> 9) & 1;
    int rest = id >> 10;            // (dir*64+slice)*NC + c
    int c    = rest % NC;
    int ds   = rest / NC;
    int slice = ds & 63;
    int dirr  = ds >> 6;
    int coll = t * 16 + (lane & 15);
    int k    = c * 32 + (lane >> 4) * 8 + j;
    int gate = coll >> 3, jjj = coll & 7;
    int zcol = gate * 512 + slice * 8 + jjj;
    const float* W = dirr ? Wb : Wf;
    const float* U = dirr ? Ub : Uf;
    float v = (k < KX) ? W[(size_t)k * NG + zcol] : U[(size_t)(k - KX) * NG + zcol];
    ((__bf16*)dst)[id] = (__bf16)v;
}

// ---------------- phase A: embedding gather into fragment-linear X + tag zero ----------------
// X element (t, b=m, e) stored at byte: t*32768 + ((e>>3)*64 + m)*16 + (e&7)*2
__global__ void gather_x_kernel(const int* __restrict__ tokens, const float* __restrict__ emb,
                                char* __restrict__ ws)
{
    size_t id = (size_t)blockIdx.x * 256 + threadIdx.x;
    int j  = (int)(id & 7);
    int m  = (int)((id >> 3) & 63);
    int kb = (int)((id >> 9) & 31);
    int t  = (int)(id >> 14);
    int tok = tokens[m * TSEQ + t];
    float v = emb[(size_t)tok * NE + kb * 8 + j];
    ((__bf16*)(ws + OFF_X))[(size_t)t * 16384 + (kb * 64 + m) * 8 + j] = (__bf16)v;
    if (id < 16384) ((int*)(ws + OFF_CNT))[id] = 0;    // all tag replicas
}

// ---------------- phase B: persistent pipelined recurrence ----------------
// Proven protocol: ring depth 4 (slot stride 32768 bf16), x16-replicated tags
// (R8 proved replication load-bearing: single line-set costs +1 us/step from
// read-while-written contention), drained tag publish (R2 proved drain removal
// is repaid as validate-retry quanta), coalesced full-line h stores (R4).
template<int LAYER>
__device__ void run_layer(char* __restrict__ ws, const char* __restrict__ smem,
                          int dir, int slice, int tid,
                          const float* __restrict__ bb)
{
    const int lane = tid & 63;
    const int wv   = tid >> 6;
    const int colc = lane & 15;
    const int q    = lane >> 4;
    const int m0   = wv * 16;
    const int jj   = colc & 7;
    const int hcol = slice * 8 + jj;

    __bf16* h1ring = (__bf16*)(ws + OFF_H1 + (size_t)dir * (4 * 65536));
    __bf16* h2ring = (__bf16*)(ws + OFF_H2 + (size_t)dir * (4 * 65536));
    const char* Xfrag = ws + OFF_X;
    __bf16* hfin = (__bf16*)(ws + OFF_HF) + (size_t)dir * (NB * NH);

    // tags: T[(dir*2+layer)*4096 + rep*256 + wv*64 + slice]
    int* T = (int*)(ws + OFF_CNT);
    const int rep = ((slice << 2) | wv) & 15;
    int* p1   = T + (dir * 2 + 0) * 4096 + rep * 256 + wv * 64 + lane;   // poll L1 producers
    int* p2   = T + (dir * 2 + 1) * 4096 + rep * 256 + wv * 64 + lane;   // poll L2 producers
    int* ownb = T + (dir * 2 + LAYER) * 4096;                             // publish base

    const float bi  = bb[hcol];
    const float bf_ = bb[512 + hcol];
    const float bg  = bb[1024 + hcol];
    const float bo  = bb[1536 + hcol];

    float cst[4] = {0.f, 0.f, 0.f, 0.f};

    // h-fragment element offset for consumer loads (in __bf16 units)
    const int aoff = (m0 + colc) * 8;

    #pragma unroll 1
    for (int s = 0; s < TSEQ; ++s) {
        v4f acc0a = {0,0,0,0}, acc1a = {0,0,0,0};
        v4f acc0b = {0,0,0,0}, acc1b = {0,0,0,0};

        // ---- L1: x-part (no step dependency) computed BEFORE the poll ----
        if (LAYER == 0) {
            const int xs = dir ? (TSEQ - 1 - s) : s;
            const char* xb = Xfrag + (size_t)xs * 32768;
            #pragma unroll
            for (int c = 0; c < 8; ++c) {
                v8bf a  = *(const v8bf*)(xb + (((4 * c + q) * 64 + m0 + colc) * 16));
                v8bf w0 = *(const v8bf*)(smem + (c * 2 + 0) * 1024 + lane * 16);
                v8bf w1 = *(const v8bf*)(smem + (c * 2 + 1) * 1024 + lane * 16);
                if (c & 1) { acc0b = MFMA16(a, w0, acc0b); acc1b = MFMA16(a, w1, acc1b); }
                else       { acc0a = MFMA16(a, w0, acc0a); acc1a = MFMA16(a, w1, acc1a); }
            }
        }

        // ---- lane-parallel poll on replicated per-wave tags ----
        // L1 step s: p1 >= s (h1[s-1] ready), p2 >= s-3 (ring guard)
        // L2 step s: p1 >= s+1 (h1[s] ready), p2 >= s (h2[s-1] ready)
        {
            const int t1 = LAYER ? s + 1 : s;
            const int t2 = LAYER ? s : s - 3;
            if (t1 > 0) {
                while (true) {
                    int v1 = __hip_atomic_load(p1, __ATOMIC_RELAXED, __HIP_MEMORY_SCOPE_AGENT);
                    bool ok = (v1 >= t1);
                    if (t2 > 0) {
                        int v2 = __hip_atomic_load(p2, __ATOMIC_RELAXED, __HIP_MEMORY_SCOPE_AGENT);
                        ok = ok && (v2 >= t2);
                    }
                    if (__all(ok)) break;
                }
            }
        }

        // ---- h-dependent MFMA work (coalesced coherent loads, LDS weights) ----
        if (LAYER == 0) {
            if (s > 0) {
                const __bf16* hb = h1ring + (size_t)((s - 1) & 3) * 32768;
                v8bf ah[16];
                #pragma unroll
                for (int c = 0; c < 16; ++c)
                    ah[c] = load_h8(hb + (4 * c + q) * 512 + aoff);
                __builtin_amdgcn_sched_barrier(0);   // keep the load batch together
                #pragma unroll
                for (int c = 0; c < 16; ++c) {
                    v8bf w0 = *(const v8bf*)(smem + ((8 + c) * 2 + 0) * 1024 + lane * 16);
                    v8bf w1 = *(const v8bf*)(smem + ((8 + c) * 2 + 1) * 1024 + lane * 16);
                    if (c & 1) { acc0b = MFMA16(ah[c], w0, acc0b); acc1b = MFMA16(ah[c], w1, acc1b); }
                    else       { acc0a = MFMA16(ah[c], w0, acc0a); acc1a = MFMA16(ah[c], w1, acc1a); }
                }
            }
        } else {
            const __bf16* hb1 = h1ring + (size_t)(s & 3) * 32768;
            v8bf a0[16], a1[16];
            #pragma unroll
            for (int c = 0; c < 16; ++c)
                a0[c] = load_h8(hb1 + (4 * c + q) * 512 + aoff);
            if (s > 0) {
                const __bf16* hb2 = h2ring + (size_t)((s - 1) & 3) * 32768;
                #pragma unroll
                for (int c = 0; c < 16; ++c)
                    a1[c] = load_h8(hb2 + (4 * c + q) * 512 + aoff);
            }
            __builtin_amdgcn_sched_barrier(0);
            #pragma unroll
            for (int c = 0; c < 16; ++c) {
                v8bf w0 = *(const v8bf*)(smem + (c * 2 + 0) * 1024 + lane * 16);
                v8bf w1 = *(const v8bf*)(smem + (c * 2 + 1) * 1024 + lane * 16);
                if (c & 1) { acc0b = MFMA16(a0[c], w0, acc0b); acc1b = MFMA16(a0[c], w1, acc1b); }
                else       { acc0a = MFMA16(a0[c], w0, acc0a); acc1a = MFMA16(a0[c], w1, acc1a); }
            }
            if (s > 0) {
                #pragma unroll
                for (int c = 0; c < 16; ++c) {
                    v8bf w0 = *(const v8bf*)(smem + ((16 + c) * 2 + 0) * 1024 + lane * 16);
                    v8bf w1 = *(const v8bf*)(smem + ((16 + c) * 2 + 1) * 1024 + lane * 16);
                    if (c & 1) { acc0b = MFMA16(a1[c], w0, acc0b); acc1b = MFMA16(a1[c], w1, acc1b); }
                    else       { acc0a = MFMA16(a1[c], w0, acc0a); acc1a = MFMA16(a1[c], w1, acc1a); }
                }
            }
        }

        v4f z0 = acc0a + acc0b;   // gates i (cols 0-7) / f (cols 8-15)
        v4f z1 = acc1a + acc1b;   // gates g / o

        // ---- gate nonlinearity; lanes col and col^8 exchange ----
        float hv[4];
        #pragma unroll
        for (int r = 0; r < 4; ++r) {
            float p0 = __shfl_xor(z0[r], 8, 64);
            float p1 = __shfl_xor(z1[r], 8, 64);
            float zi, zf, zg, zo;
            if (colc < 8) { zi = z0[r]; zf = p0;    zg = z1[r]; zo = p1;    }
            else          { zi = p0;    zf = z0[r]; zg = p1;    zo = z1[r]; }
            zi += bi; zf += bf_; zg += bg; zo += bo;
            float gi = 1.f / (1.f + __expf(-zi));
            float gf = 1.f / (1.f + __expf(-zf));
            float gg = 1.f - 2.f / (1.f + __expf(2.f * zg));   // tanh
            float go = 1.f / (1.f + __expf(-zo));
            float cn = gf * cst[r] + gi * gg;
            cst[r] = cn;
            float th = 1.f - 2.f / (1.f + __expf(2.f * cn));   // tanh
            hv[r] = go * th;
        }

        // ---- coalesced h store: 4x4 lane transpose -> one 16B row per lane ----
        // After pair-packing (shfl_xor 1), lane (q, colc even<8) holds u[r] =
        // cols(colc,colc+1) of row m0+q*4+r. Butterfly transpose across lanes
        // colc in {0,2,4,6} (xor masks 2,4) leaves lane i=colc>>1 holding ALL
        // col-pairs of row m0+q*4+i -> two contiguous 8B stores (full lines).
        __bf16* hd = (LAYER ? h2ring : h1ring) + (size_t)(s & 3) * 32768;
        {
            unsigned u0, u1, u2, u3;
            {
                float pv0 = __shfl_xor(hv[0], 1, 64);
                float pv1 = __shfl_xor(hv[1], 1, 64);
                float pv2 = __shfl_xor(hv[2], 1, 64);
                float pv3 = __shfl_xor(hv[3], 1, 64);
                u0 = (unsigned)bf16_bits(hv[0]) | ((unsigned)bf16_bits(pv0) << 16);
                u1 = (unsigned)bf16_bits(hv[1]) | ((unsigned)bf16_bits(pv1) << 16);
                u2 = (unsigned)bf16_bits(hv[2]) | ((unsigned)bf16_bits(pv2) << 16);
                u3 = (unsigned)bf16_bits(hv[3]) | ((unsigned)bf16_bits(pv3) << 16);
            }
            const bool sel1 = (colc & 2) != 0;
            const bool sel2 = (colc & 4) != 0;
            unsigned t;
            t = __shfl_xor(sel1 ? u0 : u1, 2, 64); if (sel1) u0 = t; else u1 = t;
            t = __shfl_xor(sel1 ? u2 : u3, 2, 64); if (sel1) u2 = t; else u3 = t;
            t = __shfl_xor(sel2 ? u0 : u2, 4, 64); if (sel2) u0 = t; else u2 = t;
            t = __shfl_xor(sel2 ? u1 : u3, 4, 64); if (sel2) u1 = t; else u3 = t;
            if (((colc & 1) == 0) && (colc < 8)) {
                const int m = m0 + q * 4 + (colc >> 1);
                unsigned long long lo = (unsigned long long)u0 | ((unsigned long long)u1 << 32);
                unsigned long long hi = (unsigned long long)u2 | ((unsigned long long)u3 << 32);
                unsigned long long* dp = (unsigned long long*)(hd + (slice * 64 + m) * 8);
                __hip_atomic_store(dp,     lo, __ATOMIC_RELAXED, __HIP_MEMORY_SCOPE_AGENT);
                __hip_atomic_store(dp + 1, hi, __ATOMIC_RELAXED, __HIP_MEMORY_SCOPE_AGENT);
            }
        }
        if (LAYER == 1 && s == TSEQ - 1 && colc < 8) {
            #pragma unroll
            for (int r = 0; r < 4; ++r)
                hfin[(size_t)(m0 + q * 4 + r) * NH + hcol] = (__bf16)hv[r];   // kernel boundary
        }

        // drain this wave's stores (count-independent), then publish tag to 16 replicas
        asm volatile("s_waitcnt vmcnt(0)" ::: "memory");
        if (lane < 16)
            __hip_atomic_store(ownb + lane * 256 + wv * 64 + slice, s + 1,
                               __ATOMIC_RELAXED, __HIP_MEMORY_SCOPE_AGENT);
    }
}

__global__ __launch_bounds__(256, 1) void lstm_persist(
    char* __restrict__ ws,
    const float* __restrict__ b1f, const float* __restrict__ b2f,
    const float* __restrict__ b1b, const float* __restrict__ b2b)
{
    const int tid   = threadIdx.x;
    const int bid   = blockIdx.x;       // 256 wgs
    const int dir   = bid >> 7;
    const int layer = (bid >> 6) & 1;
    const int slice = bid & 63;

    const int NC = layer ? 32 : 24;
    const int wbytes = NC * 2048;       // 48KB (L1) / 64KB (L2)

    __shared__ char smem[65536];
    {
        const char* wsrc = ws + (layer ? OFF_W2 : OFF_W1)
                         + (size_t)(dir * 64 + slice) * (size_t)wbytes;
        for (int i = tid * 16; i < wbytes; i += 256 * 16)
            *(uint4*)(smem + i) = *(const uint4*)(wsrc + i);
    }
    __syncthreads();   // staging is cooperative; only barrier in the kernel

    const float* bb = layer ? (dir ? b2b : b2f) : (dir ? b1b : b1f);
    if (layer == 0) run_layer<0>(ws, smem, dir, slice, tid, bb);
    else            run_layer<1>(ws, smem, dir, slice, tid, bb);
}

// ---------------- phase C: dense head [64,1024]@[1024,5]+bd ----------------
__global__ void head_kernel(const char* __restrict__ ws, const float* __restrict__ Wd,
                            const float* __restrict__ bd, float* __restrict__ out)
{
    int b = blockIdx.x;
    int lane = threadIdx.x;   // 64
    const __bf16* hfF = (const __bf16*)(ws + OFF_HF) + (size_t)b * NH;
    const __bf16* hfB = (const __bf16*)(ws + OFF_HF) + (size_t)(NB * NH) + (size_t)b * NH;
    #pragma unroll
    for (int o = 0; o < 5; ++o) {
        float sum = 0.f;
        for (int k = lane; k < 2 * NH; k += 64) {
            float fv = (k < NH) ? (float)hfF[k] : (float)hfB[k - NH];
            sum += fv * Wd[(size_t)k * 5 + o];
        }
        #pragma unroll
        for (int off = 32; off > 0; off >>= 1) sum += __shfl_down(sum, off, 64);
        if (lane == 0) out[b * 5 + o] = sum + bd[o];
    }
}

// ---------------- launch ----------------
extern "C" void kernel_launch(void* const* d_in, const int* in_sizes, int n_in,
                              void* d_out, int out_size, void* d_ws, size_t ws_size,
                              hipStream_t stream)
{
    const int*   tokens = (const int*)  d_in[0];
    const float* emb    = (const float*)d_in[1];
    const float* W1f    = (const float*)d_in[2];
    const float* U1f    = (const float*)d_in[3];
    const float* b1f    = (const float*)d_in[4];
    const float* W2f    = (const float*)d_in[5];
    const float* U2f    = (const float*)d_in[6];
    const float* b2f    = (const float*)d_in[7];
    const float* W1b    = (const float*)d_in[8];
    const float* U1b    = (const float*)d_in[9];
    const float* b1b    = (const float*)d_in[10];
    const float* W2b    = (const float*)d_in[11];
    const float* U2b    = (const float*)d_in[12];
    const float* b2b    = (const float*)d_in[13];
    const float* Wd     = (const float*)d_in[14];
    const float* bd     = (const float*)d_in[15];
    char* ws = (char*)d_ws;

    wconv_kernel<<<12288, 256, 0, stream>>>(W1f, U1f, W1b, U1b, ws + OFF_W1, 24, 256);
    wconv_kernel<<<16384, 256, 0, stream>>>(W2f, U2f, W2b, U2b, ws + OFF_W2, 32, 512);
    gather_x_kernel<<<32768, 256, 0, stream>>>(tokens, emb, ws);
    lstm_persist<<<256, 256, 0, stream>>>(ws, b1f, b2f, b1b, b2b);
    head_kernel<<<NB, 64, 0, stream>>>(ws, Wd, bd, (float*)d_out);
}